// Round 1
// baseline (285.536 us; speedup 1.0000x reference)
//
#include <hip/hip_runtime.h>
#include <math.h>

typedef unsigned long long u64;

#define BB 4
#define NN 2048
#define FINE 256
#define FOUTE 256
#define HH 4
#define DD 64
#define NW 32   // 2048/64 packed words per adj row

__device__ __forceinline__ float lrelu(float x) { return fmaxf(x, 0.2f * x); }

// ---------------- K0: pack adj (B,N,N) int32 -> bitmask (B,N,NW) u64 ----------------
__global__ __launch_bounds__(256) void k_pack(const int* __restrict__ adj, u64* __restrict__ pack) {
  int row = blockIdx.x;                 // b*N + i
  int wv = threadIdx.x >> 6, ln = threadIdx.x & 63;
  const int* arow = adj + (size_t)row * NN;
  u64* prow = pack + (size_t)row * NW;
  for (int w = wv; w < NW; w += 4) {
    u64 m = __ballot(arow[(w << 6) + ln] != 0);
    if (ln == 0) prow[w] = m;
  }
}

// ---------------- K1: hp[(b*H+h)*N + n][d] = sum_k h[b,n,k] * W[h*64+d,k] ----------------
__global__ __launch_bounds__(256) void k_gemm1(const float* __restrict__ hI, const float* __restrict__ W,
                                               float* __restrict__ hp) {
  __shared__ float As[16][65];
  __shared__ float Bs[16][65];
  int m0 = blockIdx.x * 64;             // over M = B*N
  int hh = blockIdx.y;                  // head == 64-col tile of FOUT
  int f0 = hh * 64;
  int tid = threadIdx.x;
  int ti = tid >> 4, td = tid & 15;
  int lr = tid >> 2, kg = (tid & 3) << 2;
  float acc[4][4] = {};
  for (int k0 = 0; k0 < FINE; k0 += 16) {
    float4 va = *(const float4*)&hI[(size_t)(m0 + lr) * FINE + k0 + kg];
    float4 vb = *(const float4*)&W[(size_t)(f0 + lr) * FINE + k0 + kg];
    As[kg + 0][lr] = va.x; As[kg + 1][lr] = va.y; As[kg + 2][lr] = va.z; As[kg + 3][lr] = va.w;
    Bs[kg + 0][lr] = vb.x; Bs[kg + 1][lr] = vb.y; Bs[kg + 2][lr] = vb.z; Bs[kg + 3][lr] = vb.w;
    __syncthreads();
#pragma unroll
    for (int kk = 0; kk < 16; ++kk) {
      float a[4], b[4];
#pragma unroll
      for (int r = 0; r < 4; ++r) a[r] = As[kk][(ti << 2) + r];
#pragma unroll
      for (int c = 0; c < 4; ++c) b[c] = Bs[kk][(td << 2) + c];
#pragma unroll
      for (int r = 0; r < 4; ++r)
#pragma unroll
        for (int c = 0; c < 4; ++c) acc[r][c] += a[r] * b[c];
    }
    __syncthreads();
  }
#pragma unroll
  for (int r = 0; r < 4; ++r) {
    int m = m0 + (ti << 2) + r;
    int b = m >> 11, n = m & (NN - 1);
    float4 o = make_float4(acc[r][0], acc[r][1], acc[r][2], acc[r][3]);
    *(float4*)&hp[((size_t)(b * HH + hh) * NN + n) * DD + (td << 2)] = o;
  }
}

// ---------------- K2: s,t per (b,h,n): dot(hp_row, a_src/a_dst) ----------------
__global__ __launch_bounds__(256) void k_st(const float* __restrict__ hp, const float* __restrict__ attn,
                                            float* __restrict__ sB, float* __restrict__ tB) {
  int row = (blockIdx.x << 2) + (threadIdx.x >> 6);  // (b*H+h)*N + n
  int ln = threadIdx.x & 63;
  int hh = (row >> 11) & 3;
  float v = hp[((size_t)row << 6) + ln];
  float ps = v * attn[(hh << 7) + ln];
  float pt = v * attn[(hh << 7) + 64 + ln];
#pragma unroll
  for (int off = 32; off; off >>= 1) { ps += __shfl_down(ps, off); pt += __shfl_down(pt, off); }
  if (ln == 0) { sB[row] = ps; tB[row] = pt; }
}

// ---------------- K3: per (b,i) row: m_h = lrelu(s + max_valid t), l_h = sum exp ----------------
__global__ __launch_bounds__(256) void k_ml(const float* __restrict__ sB, const float* __restrict__ tB,
                                            const u64* __restrict__ pack,
                                            float* __restrict__ mB, float* __restrict__ rlB) {
  __shared__ float4 red[256];
  int row = blockIdx.x;                 // b*N+i
  int b = row >> 11, i = row & (NN - 1);
  int tid = threadIdx.x;
  const u64* prow = pack + (size_t)row * NW;
  const float* t0 = tB + (size_t)(b * HH) * NN;
  float4 tm = make_float4(-1e30f, -1e30f, -1e30f, -1e30f);
  for (int j = tid; j < NN; j += 256) {
    if ((prow[j >> 6] >> (j & 63)) & 1ull) {
      tm.x = fmaxf(tm.x, t0[j]);
      tm.y = fmaxf(tm.y, t0[NN + j]);
      tm.z = fmaxf(tm.z, t0[2 * NN + j]);
      tm.w = fmaxf(tm.w, t0[3 * NN + j]);
    }
  }
  red[tid] = tm; __syncthreads();
  for (int st = 128; st; st >>= 1) {
    if (tid < st) {
      float4 o = red[tid + st];
      tm.x = fmaxf(tm.x, o.x); tm.y = fmaxf(tm.y, o.y);
      tm.z = fmaxf(tm.z, o.z); tm.w = fmaxf(tm.w, o.w);
      red[tid] = tm;
    }
    __syncthreads();
  }
  tm = red[0];
  __syncthreads();
  float sv[4], mh[4];
#pragma unroll
  for (int h = 0; h < 4; ++h) sv[h] = sB[(size_t)(b * HH + h) * NN + i];
  mh[0] = lrelu(sv[0] + tm.x); mh[1] = lrelu(sv[1] + tm.y);
  mh[2] = lrelu(sv[2] + tm.z); mh[3] = lrelu(sv[3] + tm.w);
  float4 ls = make_float4(0.f, 0.f, 0.f, 0.f);
  for (int j = tid; j < NN; j += 256) {
    if ((prow[j >> 6] >> (j & 63)) & 1ull) {
      ls.x += __expf(lrelu(sv[0] + t0[j]) - mh[0]);
      ls.y += __expf(lrelu(sv[1] + t0[NN + j]) - mh[1]);
      ls.z += __expf(lrelu(sv[2] + t0[2 * NN + j]) - mh[2]);
      ls.w += __expf(lrelu(sv[3] + t0[3 * NN + j]) - mh[3]);
    }
  }
  red[tid] = ls; __syncthreads();
  for (int st = 128; st; st >>= 1) {
    if (tid < st) {
      float4 o = red[tid + st];
      ls.x += o.x; ls.y += o.y; ls.z += o.z; ls.w += o.w;
      red[tid] = ls;
    }
    __syncthreads();
  }
  if (tid < 4) {
    float4 tot = red[0];
    float l = (&tot.x)[tid];
    mB[(size_t)(b * HH + tid) * NN + i] = mh[tid];
    rlB[(size_t)(b * HH + tid) * NN + i] = 1.0f / l;
  }
}

// ---------------- K4: h_new = alpha @ hp, per (b,h,i-tile of 64) ----------------
__global__ __launch_bounds__(256) void k_pv(const float* __restrict__ hp, const float* __restrict__ sB,
                                            const float* __restrict__ tB, const float* __restrict__ mB,
                                            const float* __restrict__ rlB, const u64* __restrict__ pack,
                                            float* __restrict__ out) {
  __shared__ float sP[64], mP[64], rlP[64], tJ[64];
  __shared__ unsigned adjLo[64], adjHi[64];
  __shared__ float aT[64 * 64];   // [jj][ii]
  __shared__ float bT[64 * 64];   // [jj][d]
  int blk = blockIdx.x;
  int it = blk & 31, bh = blk >> 5;
  int b = bh >> 2, hh = bh & 3;
  int i0 = it << 6;
  int tid = threadIdx.x;
  int ti = tid >> 4, td = tid & 15;
  if (tid < 64) {
    size_t r = (size_t)bh * NN + i0 + tid;
    sP[tid] = sB[r]; mP[tid] = mB[r]; rlP[tid] = rlB[r];
  }
  float acc[4][4] = {};
  int iiA = tid & 63, jg = (tid >> 6) << 4;   // phase-A mapping: lane sweeps ii, loop sweeps jj
  for (int jc = 0; jc < 32; ++jc) {
    int j0 = jc << 6;
    __syncthreads();
    if (tid < 64) {
      u64 w = pack[((size_t)(b * NN) + i0 + tid) * NW + jc];
      adjLo[tid] = (unsigned)w; adjHi[tid] = (unsigned)(w >> 32);
    } else if (tid < 128) {
      tJ[tid - 64] = tB[(size_t)bh * NN + j0 + (tid - 64)];
    }
#pragma unroll
    for (int q = 0; q < 4; ++q) {
      int idx = tid + (q << 8);
      int rw = idx >> 4, c4 = (idx & 15) << 2;
      *(float4*)&bT[(rw << 6) + c4] = *(const float4*)&hp[((size_t)bh * NN + j0 + rw) * DD + c4];
    }
    __syncthreads();
    // phase A: alpha tile (conflict-free writes: lanes contiguous over ii)
    {
      float si = sP[iiA], mi = mP[iiA], ri = rlP[iiA];
      unsigned lo = adjLo[iiA], hi = adjHi[iiA];
#pragma unroll
      for (int r = 0; r < 16; ++r) {
        int jj = jg + r;
        unsigned word = (jj & 32) ? hi : lo;
        float bit = (float)((word >> (jj & 31)) & 1u);
        float x = si + tJ[jj];
        float al = bit * __expf(lrelu(x) - mi) * ri;
        aT[(jj << 6) + iiA] = al;
      }
    }
    __syncthreads();
    // phase B: acc += alpha_tile^T-slices @ hp_tile
#pragma unroll 8
    for (int kk = 0; kk < 64; ++kk) {
      float4 a4 = *(const float4*)&aT[(kk << 6) + (ti << 2)];
      float4 b4 = *(const float4*)&bT[(kk << 6) + (td << 2)];
      acc[0][0] += a4.x * b4.x; acc[0][1] += a4.x * b4.y; acc[0][2] += a4.x * b4.z; acc[0][3] += a4.x * b4.w;
      acc[1][0] += a4.y * b4.x; acc[1][1] += a4.y * b4.y; acc[1][2] += a4.y * b4.z; acc[1][3] += a4.y * b4.w;
      acc[2][0] += a4.z * b4.x; acc[2][1] += a4.z * b4.y; acc[2][2] += a4.z * b4.z; acc[2][3] += a4.z * b4.w;
      acc[3][0] += a4.w * b4.x; acc[3][1] += a4.w * b4.y; acc[3][2] += a4.w * b4.z; acc[3][3] += a4.w * b4.w;
    }
  }
#pragma unroll
  for (int r = 0; r < 4; ++r) {
    int i = i0 + (ti << 2) + r;
    float4 o = make_float4(acc[r][0], acc[r][1], acc[r][2], acc[r][3]);
    *(float4*)&out[((size_t)(b * NN + i)) * FOUTE + (hh << 6) + (td << 2)] = o;
  }
}

// ---------------- K5: alpha mean over heads ----------------
__global__ __launch_bounds__(256) void k_mean(const float* __restrict__ sB, const float* __restrict__ tB,
                                              const float* __restrict__ mB, const float* __restrict__ rlB,
                                              const u64* __restrict__ pack, float* __restrict__ outMean) {
  int row = blockIdx.x;                 // b*N + i
  int b = row >> 11, i = row & (NN - 1);
  int tid = threadIdx.x;
  float sv[4], mv[4], rv[4];
#pragma unroll
  for (int h = 0; h < 4; ++h) {
    size_t idx = (size_t)(b * HH + h) * NN + i;
    sv[h] = sB[idx]; mv[h] = mB[idx]; rv[h] = rlB[idx];
  }
  const u64* prow = pack + (size_t)row * NW;
  const float* t0 = tB + (size_t)(b * HH) * NN;
  float* orow = outMean + (size_t)row * NN;
  for (int j = tid; j < NN; j += 256) {
    float bit = (float)((prow[j >> 6] >> (j & 63)) & 1ull);
    float a0 = __expf(lrelu(sv[0] + t0[j]) - mv[0]) * rv[0];
    float a1 = __expf(lrelu(sv[1] + t0[NN + j]) - mv[1]) * rv[1];
    float a2 = __expf(lrelu(sv[2] + t0[2 * NN + j]) - mv[2]) * rv[2];
    float a3 = __expf(lrelu(sv[3] + t0[3 * NN + j]) - mv[3]) * rv[3];
    orow[j] = 0.25f * bit * (a0 + a1 + a2 + a3);
  }
}

extern "C" void kernel_launch(void* const* d_in, const int* in_sizes, int n_in,
                              void* d_out, int out_size, void* d_ws, size_t ws_size,
                              hipStream_t stream) {
  const float* hIn  = (const float*)d_in[0];
  const int*   adj  = (const int*)d_in[1];
  const float* W    = (const float*)d_in[2];
  const float* attn = (const float*)d_in[3];
  float* out = (float*)d_out;
  float* outMean = out + (size_t)BB * NN * FOUTE;

  // workspace layout (fp32 elements): hp | s | t | m | 1/l | packed adj bits
  float* ws = (float*)d_ws;
  float* hp  = ws;                                  // 2,097,152
  float* sB  = hp + (size_t)BB * HH * NN * DD;      // 32,768
  float* tB  = sB + BB * HH * NN;
  float* mB  = tB + BB * HH * NN;
  float* rlB = mB + BB * HH * NN;
  u64* pack  = (u64*)(rlB + BB * HH * NN);          // 262,144 u64 (2 MB) — total ~11 MB

  hipLaunchKernelGGL(k_pack,  dim3(BB * NN), dim3(256), 0, stream, adj, pack);
  hipLaunchKernelGGL(k_gemm1, dim3((BB * NN) / 64, FOUTE / 64), dim3(256), 0, stream, hIn, W, hp);
  hipLaunchKernelGGL(k_st,    dim3((BB * HH * NN) / 4), dim3(256), 0, stream, hp, attn, sB, tB);
  hipLaunchKernelGGL(k_ml,    dim3(BB * NN), dim3(256), 0, stream, sB, tB, pack, mB, rlB);
  hipLaunchKernelGGL(k_pv,    dim3(BB * HH * (NN / 64)), dim3(256), 0, stream, hp, sB, tB, mB, rlB, pack, out);
  hipLaunchKernelGGL(k_mean,  dim3(BB * NN), dim3(256), 0, stream, sB, tB, mB, rlB, pack, outMean);
}

// Round 2
// 164.804 us; speedup vs baseline: 1.7326x; 1.7326x over previous
//
#include <hip/hip_runtime.h>
#include <math.h>

typedef unsigned long long u64;
typedef unsigned short ushort_t;
typedef float f32x4 __attribute__((ext_vector_type(4)));
typedef short short8 __attribute__((ext_vector_type(8)));

#define BB 4
#define NN 2048
#define FINE 256
#define FOUTE 256
#define HH 4
#define DD 64
#define NW 32   // 2048/64 packed words per adj row

__device__ __forceinline__ float lrelu(float x) { return fmaxf(x, 0.2f * x); }

__device__ __forceinline__ unsigned short f2bf(float x) {   // fp32 -> bf16 RNE
  unsigned u = __float_as_uint(x);
  unsigned r = u + 0x7FFFu + ((u >> 16) & 1u);
  return (unsigned short)(r >> 16);
}

// ---------------- K0: pack adj (B,N,N) int32 -> bitmask (B,N,NW) u64 ----------------
__global__ __launch_bounds__(256) void k_pack(const int* __restrict__ adj, u64* __restrict__ pack) {
  int row = blockIdx.x;                 // b*N + i
  int wv = threadIdx.x >> 6, ln = threadIdx.x & 63;
  const int* arow = adj + (size_t)row * NN;
  u64* prow = pack + (size_t)row * NW;
  for (int w = wv; w < NW; w += 4) {
    u64 m = __ballot(arow[(w << 6) + ln] != 0);
    if (ln == 0) prow[w] = m;
  }
}

// ---------------- K1: projection GEMM + fused s/t + transposed bf16 hp ----------------
// hpT[(b*H+h)*64 + d][n] = bf16( sum_k h[b,n,k] * W[h*64+d,k] )
// s[(b*H+h)*N + n] = dot(hp_row, a_src);  t likewise with a_dst.
__global__ __launch_bounds__(256) void k_gemm1(const float* __restrict__ hI, const float* __restrict__ W,
                                               const float* __restrict__ attn,
                                               ushort_t* __restrict__ hpT,
                                               float* __restrict__ sB, float* __restrict__ tB) {
  __shared__ float As[16][65];
  __shared__ float Bs[16][65];
  __shared__ ushort_t tT[64][72];       // transposed bf16 tile [d][n], padded (144B rows, 16B-aligned segs)
  int m0 = blockIdx.x * 64;             // over M = B*N
  int hh = blockIdx.y;                  // head == 64-col tile of FOUT
  int f0 = hh * 64;
  int tid = threadIdx.x;
  int ti = tid >> 4, td = tid & 15;
  int lr = tid >> 2, kg = (tid & 3) << 2;
  float acc[4][4] = {};
  for (int k0 = 0; k0 < FINE; k0 += 16) {
    float4 va = *(const float4*)&hI[(size_t)(m0 + lr) * FINE + k0 + kg];
    float4 vb = *(const float4*)&W[(size_t)(f0 + lr) * FINE + k0 + kg];
    As[kg + 0][lr] = va.x; As[kg + 1][lr] = va.y; As[kg + 2][lr] = va.z; As[kg + 3][lr] = va.w;
    Bs[kg + 0][lr] = vb.x; Bs[kg + 1][lr] = vb.y; Bs[kg + 2][lr] = vb.z; Bs[kg + 3][lr] = vb.w;
    __syncthreads();
#pragma unroll
    for (int kk = 0; kk < 16; ++kk) {
      float a[4], b[4];
#pragma unroll
      for (int r = 0; r < 4; ++r) a[r] = As[kk][(ti << 2) + r];
#pragma unroll
      for (int c = 0; c < 4; ++c) b[c] = Bs[kk][(td << 2) + c];
#pragma unroll
      for (int r = 0; r < 4; ++r)
#pragma unroll
        for (int c = 0; c < 4; ++c) acc[r][c] += a[r] * b[c];
    }
    __syncthreads();
  }
  // ---- fused s/t: reduce over td (lanes sharing the same rows) ----
  float as4[4], ad4[4];
#pragma unroll
  for (int c = 0; c < 4; ++c) {
    as4[c] = attn[(hh << 7) + (td << 2) + c];
    ad4[c] = attn[(hh << 7) + 64 + (td << 2) + c];
  }
  float ps[4] = {0.f, 0.f, 0.f, 0.f}, pt[4] = {0.f, 0.f, 0.f, 0.f};
#pragma unroll
  for (int r = 0; r < 4; ++r)
#pragma unroll
    for (int c = 0; c < 4; ++c) { ps[r] += acc[r][c] * as4[c]; pt[r] += acc[r][c] * ad4[c]; }
#pragma unroll
  for (int off = 1; off <= 8; off <<= 1) {
#pragma unroll
    for (int r = 0; r < 4; ++r) { ps[r] += __shfl_xor(ps[r], off); pt[r] += __shfl_xor(pt[r], off); }
  }
  int b0 = m0 >> 11, n0 = m0 & (NN - 1);
  if (td == 0) {
#pragma unroll
    for (int r = 0; r < 4; ++r) {
      int nn = n0 + (ti << 2) + r;
      size_t idx = (size_t)(b0 * HH + hh) * NN + nn;
      sB[idx] = ps[r]; tB[idx] = pt[r];
    }
  }
  // ---- transposed bf16 store via LDS ----
#pragma unroll
  for (int r = 0; r < 4; ++r)
#pragma unroll
    for (int c = 0; c < 4; ++c) tT[(td << 2) + c][(ti << 2) + r] = f2bf(acc[r][c]);
  __syncthreads();
#pragma unroll
  for (int q = 0; q < 2; ++q) {
    int dr = (q << 5) + (tid >> 3);
    int seg = tid & 7;
    *(short8*)&hpT[((size_t)((b0 * HH + hh) << 6) + dr) * NN + n0 + (seg << 3)] =
        *(const short8*)&tT[dr][seg << 3];
  }
}

// ---------------- K2: per (b,i): c_h = m_h + ln(l_h), m_h = lrelu(s + max_valid t) ----------------
__global__ __launch_bounds__(256) void k_ml(const float* __restrict__ sB, const float* __restrict__ tB,
                                            const u64* __restrict__ pack, float* __restrict__ cB) {
  __shared__ float4 red[256];
  int row = blockIdx.x;                 // b*N+i
  int b = row >> 11, i = row & (NN - 1);
  int tid = threadIdx.x;
  const u64* prow = pack + (size_t)row * NW;
  const float* t0 = tB + (size_t)(b * HH) * NN;
  float4 tm = make_float4(-1e30f, -1e30f, -1e30f, -1e30f);
  for (int j = tid; j < NN; j += 256) {
    if ((prow[j >> 6] >> (j & 63)) & 1ull) {
      tm.x = fmaxf(tm.x, t0[j]);
      tm.y = fmaxf(tm.y, t0[NN + j]);
      tm.z = fmaxf(tm.z, t0[2 * NN + j]);
      tm.w = fmaxf(tm.w, t0[3 * NN + j]);
    }
  }
  red[tid] = tm; __syncthreads();
  for (int st = 128; st; st >>= 1) {
    if (tid < st) {
      float4 o = red[tid + st];
      tm.x = fmaxf(tm.x, o.x); tm.y = fmaxf(tm.y, o.y);
      tm.z = fmaxf(tm.z, o.z); tm.w = fmaxf(tm.w, o.w);
      red[tid] = tm;
    }
    __syncthreads();
  }
  tm = red[0];
  __syncthreads();
  float sv[4], mh[4];
#pragma unroll
  for (int h = 0; h < 4; ++h) sv[h] = sB[(size_t)(b * HH + h) * NN + i];
  mh[0] = lrelu(sv[0] + tm.x); mh[1] = lrelu(sv[1] + tm.y);
  mh[2] = lrelu(sv[2] + tm.z); mh[3] = lrelu(sv[3] + tm.w);
  float4 ls = make_float4(0.f, 0.f, 0.f, 0.f);
  for (int j = tid; j < NN; j += 256) {
    if ((prow[j >> 6] >> (j & 63)) & 1ull) {
      ls.x += __expf(lrelu(sv[0] + t0[j]) - mh[0]);
      ls.y += __expf(lrelu(sv[1] + t0[NN + j]) - mh[1]);
      ls.z += __expf(lrelu(sv[2] + t0[2 * NN + j]) - mh[2]);
      ls.w += __expf(lrelu(sv[3] + t0[3 * NN + j]) - mh[3]);
    }
  }
  red[tid] = ls; __syncthreads();
  for (int st = 128; st; st >>= 1) {
    if (tid < st) {
      float4 o = red[tid + st];
      ls.x += o.x; ls.y += o.y; ls.z += o.z; ls.w += o.w;
      red[tid] = ls;
    }
    __syncthreads();
  }
  if (tid < 4) {
    float4 tot = red[0];
    float l = (&tot.x)[tid];
    cB[(size_t)(b * HH + tid) * NN + i] = mh[tid] + __logf(l);
  }
}

// ---------------- K3: h_new = alpha @ hp via bf16 MFMA; alpha generated in A-frag regs ----------------
// grid: (bh 0..15) x (i-tile 0..31); 256 threads = 4 waves, wave w owns i-rows [i0+16w, i0+16w+16)
__global__ __launch_bounds__(256) void k_pv(const ushort_t* __restrict__ hpT,
                                            const float* __restrict__ sB, const float* __restrict__ cB,
                                            const float* __restrict__ tB, const u64* __restrict__ pack,
                                            float* __restrict__ out) {
  __shared__ ushort_t hpTile[2][4096];  // [buf][64 d-rows][64 j] bf16, XOR-swizzled (slot ^= drow&7)
  int blk = blockIdx.x;
  int it = blk & 31, bh = blk >> 5;
  int b = bh >> 2, hh = bh & 3;
  int i0 = it << 6;
  int tid = threadIdx.x;
  int w = tid >> 6, lane = tid & 63;
  int li = lane & 15, g = lane >> 4;
  int irow = i0 + (w << 4) + li;        // alpha row this lane generates
  float sI = sB[(size_t)bh * NN + irow];
  float cI = cB[(size_t)bh * NN + irow];
  const u64* packRow = pack + ((size_t)b * NN + irow) * NW;
  const float* tRow = tB + (size_t)bh * NN;

  // staging: wave w loads drows [16w,16w+16); lds dest linear, global src pre-swizzled
  int drow0 = (w << 4) + (lane >> 3);           // q=0 rows; q=1 adds 8
  int xslot = (lane & 7) ^ (lane >> 3);         // (slot ^ drow&7); same for q=0/1
  const ushort_t* srcBase0 = hpT + ((size_t)(bh << 6) + drow0) * NN + (xslot << 3);
  const ushort_t* srcBase1 = srcBase0 + (size_t)8 * NN;

#define STAGE(buf, j0c)                                                                        \
  do {                                                                                         \
    __builtin_amdgcn_global_load_lds(                                                          \
        (const __attribute__((address_space(1))) void*)(srcBase0 + (j0c)),                     \
        (__attribute__((address_space(3))) void*)&hpTile[buf][(w << 10)], 16, 0, 0);           \
    __builtin_amdgcn_global_load_lds(                                                          \
        (const __attribute__((address_space(1))) void*)(srcBase1 + (j0c)),                     \
        (__attribute__((address_space(3))) void*)&hpTile[buf][(w << 10) + 512], 16, 0, 0);     \
  } while (0)

  f32x4 acc[4] = {};
  int cur = 0;
  STAGE(0, 0);
  asm volatile("s_waitcnt vmcnt(0)" ::: "memory");
  __syncthreads();

  for (int jc = 0; jc < 32; ++jc) {
    int j0 = jc << 6;
    u64 wbits = packRow[jc];
    const float4* tp4 = (const float4*)(tRow + j0 + (g << 3));
    float4 ta0 = tp4[0], ta1 = tp4[1], tb0 = tp4[8], tb1 = tp4[9];
    if (jc < 31) STAGE(cur ^ 1, (jc + 1) << 6);

    // alpha A-fragments: lane holds rows li, k = 8g..8g+7 (ks=0) and 32+8g.. (ks=1)
    float tva[8] = {ta0.x, ta0.y, ta0.z, ta0.w, ta1.x, ta1.y, ta1.z, ta1.w};
    float tvb[8] = {tb0.x, tb0.y, tb0.z, tb0.w, tb1.x, tb1.y, tb1.z, tb1.w};
    unsigned bits0 = (unsigned)(wbits >> (g << 3));
    unsigned bits1 = (unsigned)(wbits >> (32 + (g << 3)));
    short8 a0, a1;
#pragma unroll
    for (int jj = 0; jj < 8; ++jj) {
      float x = sI + tva[jj];
      float e = __expf(fmaxf(x, 0.2f * x) - cI);
      a0[jj] = (short)(((bits0 >> jj) & 1u) ? f2bf(e) : (unsigned short)0);
      float y = sI + tvb[jj];
      float e2 = __expf(fmaxf(y, 0.2f * y) - cI);
      a1[jj] = (short)(((bits1 >> jj) & 1u) ? f2bf(e2) : (unsigned short)0);
    }

    const char* tile = (const char*)hpTile[cur];
#pragma unroll
    for (int f = 0; f < 4; ++f) {
      int dr = (f << 4) + li;
      int ro = dr << 7;
      int sw = (dr & 7) << 4;
      short8 b0 = *(const short8*)(tile + ro + ((g << 4) ^ sw));
      short8 b1 = *(const short8*)(tile + ro + ((64 + (g << 4)) ^ sw));
      acc[f] = __builtin_amdgcn_mfma_f32_16x16x32_bf16(a0, b0, acc[f], 0, 0, 0);
      acc[f] = __builtin_amdgcn_mfma_f32_16x16x32_bf16(a1, b1, acc[f], 0, 0, 0);
    }
    asm volatile("s_waitcnt vmcnt(0)" ::: "memory");
    __syncthreads();
    cur ^= 1;
  }
#undef STAGE

  // C/D layout: col = lane&15, row = 4*(lane>>4)+reg
#pragma unroll
  for (int f = 0; f < 4; ++f)
#pragma unroll
    for (int r = 0; r < 4; ++r) {
      int i = i0 + (w << 4) + (g << 2) + r;
      int d = (f << 4) + li;
      out[((size_t)(b * NN + i)) * FOUTE + (hh << 6) + d] = acc[f][r];
    }
}

// ---------------- K4: alpha mean over heads ----------------
__global__ __launch_bounds__(256) void k_mean(const float* __restrict__ sB, const float* __restrict__ tB,
                                              const float* __restrict__ cB, const u64* __restrict__ pack,
                                              float* __restrict__ outMean) {
  int row = blockIdx.x;                 // b*N + i
  int b = row >> 11, i = row & (NN - 1);
  int tid = threadIdx.x;
  float sv[4], cv[4];
#pragma unroll
  for (int h = 0; h < 4; ++h) {
    size_t idx = (size_t)(b * HH + h) * NN + i;
    sv[h] = sB[idx]; cv[h] = cB[idx];
  }
  const u64* prow = pack + (size_t)row * NW;
  const float* t0 = tB + (size_t)(b * HH) * NN;
  float* orow = outMean + (size_t)row * NN;
  for (int j = tid; j < NN; j += 256) {
    float bit = (float)((prow[j >> 6] >> (j & 63)) & 1ull);
    float x0 = sv[0] + t0[j];
    float x1 = sv[1] + t0[NN + j];
    float x2 = sv[2] + t0[2 * NN + j];
    float x3 = sv[3] + t0[3 * NN + j];
    float a0 = __expf(fmaxf(x0, 0.2f * x0) - cv[0]);
    float a1 = __expf(fmaxf(x1, 0.2f * x1) - cv[1]);
    float a2 = __expf(fmaxf(x2, 0.2f * x2) - cv[2]);
    float a3 = __expf(fmaxf(x3, 0.2f * x3) - cv[3]);
    orow[j] = 0.25f * bit * (a0 + a1 + a2 + a3);
  }
}

extern "C" void kernel_launch(void* const* d_in, const int* in_sizes, int n_in,
                              void* d_out, int out_size, void* d_ws, size_t ws_size,
                              hipStream_t stream) {
  const float* hIn  = (const float*)d_in[0];
  const int*   adj  = (const int*)d_in[1];
  const float* W    = (const float*)d_in[2];
  const float* attn = (const float*)d_in[3];
  float* out = (float*)d_out;
  float* outMean = out + (size_t)BB * NN * FOUTE;

  // workspace: hpT bf16 | s | t | c | packed adj bits  (~6.6 MB)
  ushort_t* hpT = (ushort_t*)d_ws;                        // 16*64*2048 ushorts = 4 MB
  float* sB = (float*)(hpT + (size_t)BB * HH * DD * NN);  // 32768 each
  float* tB = sB + BB * HH * NN;
  float* cB = tB + BB * HH * NN;
  u64* pack = (u64*)(cB + BB * HH * NN);                  // 2 MB

  hipLaunchKernelGGL(k_pack,  dim3(BB * NN), dim3(256), 0, stream, adj, pack);
  hipLaunchKernelGGL(k_gemm1, dim3((BB * NN) / 64, HH), dim3(256), 0, stream, hIn, W, attn, hpT, sB, tB);
  hipLaunchKernelGGL(k_ml,    dim3(BB * NN), dim3(256), 0, stream, sB, tB, pack, cB);
  hipLaunchKernelGGL(k_pv,    dim3(BB * HH * (NN / 64)), dim3(256), 0, stream, hpT, sB, cB, tB, pack, out);
  hipLaunchKernelGGL(k_mean,  dim3(BB * NN), dim3(256), 0, stream, sB, tB, cB, pack, outMean);
}

// Round 3
// 139.396 us; speedup vs baseline: 2.0484x; 1.1823x over previous
//
#include <hip/hip_runtime.h>
#include <math.h>

typedef unsigned long long u64;
typedef unsigned short ushort_t;
typedef float f32x4 __attribute__((ext_vector_type(4)));
typedef short short8 __attribute__((ext_vector_type(8)));

#define BB 4
#define NN 2048
#define FINE 256
#define FOUTE 256
#define HH 4
#define DD 64
#define NW 32   // 2048/64 packed words per adj row

__device__ __forceinline__ float lrelu(float x) { return fmaxf(x, 0.2f * x); }

__device__ __forceinline__ unsigned short f2bf(float x) {   // fp32 -> bf16 RNE
  unsigned u = __float_as_uint(x);
  unsigned r = u + 0x7FFFu + ((u >> 16) & 1u);
  return (unsigned short)(r >> 16);
}

// ---------------- K0: pack adj (B,N,N) int32 -> bitmask (B,N,NW) u64 ----------------
__global__ __launch_bounds__(256) void k_pack(const int* __restrict__ adj, u64* __restrict__ pack) {
  int row = blockIdx.x;                 // b*N + i
  int wv = threadIdx.x >> 6, ln = threadIdx.x & 63;
  const int* arow = adj + (size_t)row * NN;
  u64* prow = pack + (size_t)row * NW;
  for (int w = wv; w < NW; w += 4) {
    u64 m = __ballot(arow[(w << 6) + ln] != 0);
    if (ln == 0) prow[w] = m;
  }
}

// ---------------- K1: projection GEMM + fused s/t + transposed bf16 hp ----------------
// hpT[(b*H+h)*64 + d][n] = bf16( sum_k h[b,n,k] * W[h*64+d,k] )
// s[(b*H+h)*N + n] = dot(hp_row, a_src);  t likewise; also tB4[b][n][h] packed.
__global__ __launch_bounds__(256) void k_gemm1(const float* __restrict__ hI, const float* __restrict__ W,
                                               const float* __restrict__ attn,
                                               ushort_t* __restrict__ hpT,
                                               float* __restrict__ sB, float* __restrict__ tB,
                                               float* __restrict__ tB4) {
  __shared__ float As[16][65];
  __shared__ float Bs[16][65];
  __shared__ ushort_t tT[64][72];       // transposed bf16 tile [d][n], padded
  int m0 = blockIdx.x * 64;             // over M = B*N
  int hh = blockIdx.y;                  // head == 64-col tile of FOUT
  int f0 = hh * 64;
  int tid = threadIdx.x;
  int ti = tid >> 4, td = tid & 15;
  int lr = tid >> 2, kg = (tid & 3) << 2;
  float acc[4][4] = {};
  for (int k0 = 0; k0 < FINE; k0 += 16) {
    float4 va = *(const float4*)&hI[(size_t)(m0 + lr) * FINE + k0 + kg];
    float4 vb = *(const float4*)&W[(size_t)(f0 + lr) * FINE + k0 + kg];
    As[kg + 0][lr] = va.x; As[kg + 1][lr] = va.y; As[kg + 2][lr] = va.z; As[kg + 3][lr] = va.w;
    Bs[kg + 0][lr] = vb.x; Bs[kg + 1][lr] = vb.y; Bs[kg + 2][lr] = vb.z; Bs[kg + 3][lr] = vb.w;
    __syncthreads();
#pragma unroll
    for (int kk = 0; kk < 16; ++kk) {
      float a[4], b[4];
#pragma unroll
      for (int r = 0; r < 4; ++r) a[r] = As[kk][(ti << 2) + r];
#pragma unroll
      for (int c = 0; c < 4; ++c) b[c] = Bs[kk][(td << 2) + c];
#pragma unroll
      for (int r = 0; r < 4; ++r)
#pragma unroll
        for (int c = 0; c < 4; ++c) acc[r][c] += a[r] * b[c];
    }
    __syncthreads();
  }
  // ---- fused s/t: reduce over td (lanes sharing the same rows) ----
  float as4[4], ad4[4];
#pragma unroll
  for (int c = 0; c < 4; ++c) {
    as4[c] = attn[(hh << 7) + (td << 2) + c];
    ad4[c] = attn[(hh << 7) + 64 + (td << 2) + c];
  }
  float ps[4] = {0.f, 0.f, 0.f, 0.f}, pt[4] = {0.f, 0.f, 0.f, 0.f};
#pragma unroll
  for (int r = 0; r < 4; ++r)
#pragma unroll
    for (int c = 0; c < 4; ++c) { ps[r] += acc[r][c] * as4[c]; pt[r] += acc[r][c] * ad4[c]; }
#pragma unroll
  for (int off = 1; off <= 8; off <<= 1) {
#pragma unroll
    for (int r = 0; r < 4; ++r) { ps[r] += __shfl_xor(ps[r], off); pt[r] += __shfl_xor(pt[r], off); }
  }
  int b0 = m0 >> 11, n0 = m0 & (NN - 1);
  if (td == 0) {
#pragma unroll
    for (int r = 0; r < 4; ++r) {
      int nn = n0 + (ti << 2) + r;
      size_t idx = (size_t)(b0 * HH + hh) * NN + nn;
      sB[idx] = ps[r]; tB[idx] = pt[r];
      tB4[((size_t)b0 * NN + nn) * 4 + hh] = pt[r];
    }
  }
  // ---- transposed bf16 store via LDS ----
#pragma unroll
  for (int r = 0; r < 4; ++r)
#pragma unroll
    for (int c = 0; c < 4; ++c) tT[(td << 2) + c][(ti << 2) + r] = f2bf(acc[r][c]);
  __syncthreads();
#pragma unroll
  for (int q = 0; q < 2; ++q) {
    int dr = (q << 5) + (tid >> 3);
    int seg = tid & 7;
    *(short8*)&hpT[((size_t)((b0 * HH + hh) << 6) + dr) * NN + n0 + (seg << 3)] =
        *(const short8*)&tT[dr][seg << 3];
  }
}

// ---------------- K2: wave-per-row: c_h = lrelu(s + max_valid t) + ln(sum exp) ----------------
__global__ __launch_bounds__(256) void k_ml(const float* __restrict__ sB, const float* __restrict__ tB4,
                                            const u64* __restrict__ pack, float* __restrict__ cB) {
  int lane = threadIdx.x & 63;
  int row = __builtin_amdgcn_readfirstlane((blockIdx.x << 2) + (threadIdx.x >> 6));  // b*N + i
  int b = row >> 11, i = row & (NN - 1);
  const u64* prow = pack + (size_t)row * NW;
  const float4* t4 = (const float4*)tB4 + (size_t)b * NN;
  float4 tm = make_float4(-1e30f, -1e30f, -1e30f, -1e30f);
#pragma unroll 4
  for (int k = 0; k < NW; ++k) {
    if ((prow[k] >> lane) & 1ull) {
      float4 tv = t4[(k << 6) + lane];
      tm.x = fmaxf(tm.x, tv.x); tm.y = fmaxf(tm.y, tv.y);
      tm.z = fmaxf(tm.z, tv.z); tm.w = fmaxf(tm.w, tv.w);
    }
  }
#pragma unroll
  for (int off = 32; off; off >>= 1) {
    tm.x = fmaxf(tm.x, __shfl_xor(tm.x, off));
    tm.y = fmaxf(tm.y, __shfl_xor(tm.y, off));
    tm.z = fmaxf(tm.z, __shfl_xor(tm.z, off));
    tm.w = fmaxf(tm.w, __shfl_xor(tm.w, off));
  }
  float sv[4], mh[4];
#pragma unroll
  for (int h = 0; h < 4; ++h) sv[h] = sB[(size_t)(b * HH + h) * NN + i];
  mh[0] = lrelu(sv[0] + tm.x); mh[1] = lrelu(sv[1] + tm.y);
  mh[2] = lrelu(sv[2] + tm.z); mh[3] = lrelu(sv[3] + tm.w);
  float4 ls = make_float4(0.f, 0.f, 0.f, 0.f);
#pragma unroll 4
  for (int k = 0; k < NW; ++k) {
    if ((prow[k] >> lane) & 1ull) {
      float4 tv = t4[(k << 6) + lane];
      ls.x += __expf(lrelu(sv[0] + tv.x) - mh[0]);
      ls.y += __expf(lrelu(sv[1] + tv.y) - mh[1]);
      ls.z += __expf(lrelu(sv[2] + tv.z) - mh[2]);
      ls.w += __expf(lrelu(sv[3] + tv.w) - mh[3]);
    }
  }
#pragma unroll
  for (int off = 32; off; off >>= 1) {
    ls.x += __shfl_xor(ls.x, off);
    ls.y += __shfl_xor(ls.y, off);
    ls.z += __shfl_xor(ls.z, off);
    ls.w += __shfl_xor(ls.w, off);
  }
  if (lane == 0) {
    cB[(size_t)(b * HH + 0) * NN + i] = mh[0] + __logf(ls.x);
    cB[(size_t)(b * HH + 1) * NN + i] = mh[1] + __logf(ls.y);
    cB[(size_t)(b * HH + 2) * NN + i] = mh[2] + __logf(ls.z);
    cB[(size_t)(b * HH + 3) * NN + i] = mh[3] + __logf(ls.w);
  }
}

// ---------------- K3: h_new = alpha @ hp via bf16 MFMA; alpha generated in A-frag regs ----------------
__global__ __launch_bounds__(256) void k_pv(const ushort_t* __restrict__ hpT,
                                            const float* __restrict__ sB, const float* __restrict__ cB,
                                            const float* __restrict__ tB, const u64* __restrict__ pack,
                                            float* __restrict__ out) {
  __shared__ ushort_t hpTile[2][4096];  // [buf][64 d-rows][64 j] bf16, XOR-swizzled (slot ^= drow&7)
  int blk = blockIdx.x;
  int it = blk & 31, bh = blk >> 5;
  int b = bh >> 2, hh = bh & 3;
  int i0 = it << 6;
  int tid = threadIdx.x;
  int w = tid >> 6, lane = tid & 63;
  int li = lane & 15, g = lane >> 4;
  int irow = i0 + (w << 4) + li;        // alpha row this lane generates
  float sI = sB[(size_t)bh * NN + irow];
  float cI = cB[(size_t)bh * NN + irow];
  const u64* packRow = pack + ((size_t)b * NN + irow) * NW;
  const float* tRow = tB + (size_t)bh * NN;

  // staging: wave w loads drows [16w,16w+16); lds dest linear, global src pre-swizzled
  int drow0 = (w << 4) + (lane >> 3);           // q=0 rows; q=1 adds 8
  int xslot = (lane & 7) ^ (lane >> 3);         // (slot ^ drow&7); same for q=0/1
  const ushort_t* srcBase0 = hpT + ((size_t)(bh << 6) + drow0) * NN + (xslot << 3);
  const ushort_t* srcBase1 = srcBase0 + (size_t)8 * NN;

#define STAGE(buf, j0c)                                                                        \
  do {                                                                                         \
    __builtin_amdgcn_global_load_lds(                                                          \
        (const __attribute__((address_space(1))) void*)(srcBase0 + (j0c)),                     \
        (__attribute__((address_space(3))) void*)&hpTile[buf][(w << 10)], 16, 0, 0);           \
    __builtin_amdgcn_global_load_lds(                                                          \
        (const __attribute__((address_space(1))) void*)(srcBase1 + (j0c)),                     \
        (__attribute__((address_space(3))) void*)&hpTile[buf][(w << 10) + 512], 16, 0, 0);     \
  } while (0)

  f32x4 acc[4] = {};
  int cur = 0;
  STAGE(0, 0);
  asm volatile("s_waitcnt vmcnt(0)" ::: "memory");
  __syncthreads();

  for (int jc = 0; jc < 32; ++jc) {
    int j0 = jc << 6;
    u64 wbits = packRow[jc];
    const float4* tp4 = (const float4*)(tRow + j0 + (g << 3));
    float4 ta0 = tp4[0], ta1 = tp4[1], tb0 = tp4[8], tb1 = tp4[9];
    if (jc < 31) STAGE(cur ^ 1, (jc + 1) << 6);

    // alpha A-fragments: lane holds rows li, k = 8g..8g+7 (ks=0) and 32+8g.. (ks=1)
    float tva[8] = {ta0.x, ta0.y, ta0.z, ta0.w, ta1.x, ta1.y, ta1.z, ta1.w};
    float tvb[8] = {tb0.x, tb0.y, tb0.z, tb0.w, tb1.x, tb1.y, tb1.z, tb1.w};
    unsigned bits0 = (unsigned)(wbits >> (g << 3));
    unsigned bits1 = (unsigned)(wbits >> (32 + (g << 3)));
    short8 a0, a1;
#pragma unroll
    for (int jj = 0; jj < 8; ++jj) {
      float x = sI + tva[jj];
      float e = __expf(fmaxf(x, 0.2f * x) - cI);
      a0[jj] = (short)(((bits0 >> jj) & 1u) ? f2bf(e) : (unsigned short)0);
      float y = sI + tvb[jj];
      float e2 = __expf(fmaxf(y, 0.2f * y) - cI);
      a1[jj] = (short)(((bits1 >> jj) & 1u) ? f2bf(e2) : (unsigned short)0);
    }

    const char* tile = (const char*)hpTile[cur];
#pragma unroll
    for (int f = 0; f < 4; ++f) {
      int dr = (f << 4) + li;
      int ro = dr << 7;
      int sw = (dr & 7) << 4;
      short8 b0 = *(const short8*)(tile + ro + ((g << 4) ^ sw));
      short8 b1 = *(const short8*)(tile + ro + ((64 + (g << 4)) ^ sw));
      acc[f] = __builtin_amdgcn_mfma_f32_16x16x32_bf16(a0, b0, acc[f], 0, 0, 0);
      acc[f] = __builtin_amdgcn_mfma_f32_16x16x32_bf16(a1, b1, acc[f], 0, 0, 0);
    }
    asm volatile("s_waitcnt vmcnt(0)" ::: "memory");
    __syncthreads();
    cur ^= 1;
  }
#undef STAGE

  // C/D layout: col = lane&15, row = 4*(lane>>4)+reg
#pragma unroll
  for (int f = 0; f < 4; ++f)
#pragma unroll
    for (int r = 0; r < 4; ++r) {
      int i = i0 + (w << 4) + (g << 2) + r;
      int d = (f << 4) + li;
      out[((size_t)(b * NN + i)) * FOUTE + (hh << 6) + d] = acc[f][r];
    }
}

// ---------------- K4: alpha mean over heads (float4 stores, packed t) ----------------
__global__ __launch_bounds__(256) void k_mean(const float* __restrict__ sB, const float* __restrict__ tB4,
                                              const float* __restrict__ cB, const u64* __restrict__ pack,
                                              float* __restrict__ outMean) {
  int row = blockIdx.x;                 // b*N + i
  int b = row >> 11, i = row & (NN - 1);
  int tid = threadIdx.x;
  float sv[4], cv[4];
#pragma unroll
  for (int h = 0; h < 4; ++h) {
    size_t idx = (size_t)(b * HH + h) * NN + i;
    sv[h] = sB[idx]; cv[h] = cB[idx];
  }
  const u64* prow = pack + (size_t)row * NW;
  const float4* t4 = (const float4*)tB4 + (size_t)b * NN;
  float4* orow = (float4*)(outMean + (size_t)row * NN);
  for (int c = tid; c < NN / 4; c += 256) {
    int j0 = c << 2;
    unsigned bits = (unsigned)((prow[j0 >> 6] >> (j0 & 63)) & 0xFull);
    float4 o = make_float4(0.f, 0.f, 0.f, 0.f);
    if (bits) {
      float* op = &o.x;
#pragma unroll
      for (int q = 0; q < 4; ++q) {
        if ((bits >> q) & 1u) {
          float4 tv = t4[j0 + q];
          float x0 = sv[0] + tv.x, x1 = sv[1] + tv.y, x2 = sv[2] + tv.z, x3 = sv[3] + tv.w;
          float a0 = __expf(fmaxf(x0, 0.2f * x0) - cv[0]);
          float a1 = __expf(fmaxf(x1, 0.2f * x1) - cv[1]);
          float a2 = __expf(fmaxf(x2, 0.2f * x2) - cv[2]);
          float a3 = __expf(fmaxf(x3, 0.2f * x3) - cv[3]);
          op[q] = 0.25f * (a0 + a1 + a2 + a3);
        }
      }
    }
    orow[c] = o;
  }
}

extern "C" void kernel_launch(void* const* d_in, const int* in_sizes, int n_in,
                              void* d_out, int out_size, void* d_ws, size_t ws_size,
                              hipStream_t stream) {
  const float* hIn  = (const float*)d_in[0];
  const int*   adj  = (const int*)d_in[1];
  const float* W    = (const float*)d_in[2];
  const float* attn = (const float*)d_in[3];
  float* out = (float*)d_out;
  float* outMean = out + (size_t)BB * NN * FOUTE;

  // workspace: hpT bf16 | s | t | c | t4 | packed adj bits  (~7 MB)
  ushort_t* hpT = (ushort_t*)d_ws;                        // 16*64*2048 ushorts = 4 MB
  float* sB  = (float*)(hpT + (size_t)BB * HH * DD * NN); // 32768 each
  float* tB  = sB + BB * HH * NN;
  float* cB  = tB + BB * HH * NN;
  float* tB4 = cB + BB * HH * NN;                         // 32768 (packed [b][n][h])
  u64* pack  = (u64*)(tB4 + BB * HH * NN);                // 2 MB

  hipLaunchKernelGGL(k_pack,  dim3(BB * NN), dim3(256), 0, stream, adj, pack);
  hipLaunchKernelGGL(k_gemm1, dim3((BB * NN) / 64, HH), dim3(256), 0, stream, hIn, W, attn, hpT, sB, tB, tB4);
  hipLaunchKernelGGL(k_ml,    dim3((BB * NN) / 4), dim3(256), 0, stream, sB, tB4, pack, cB);
  hipLaunchKernelGGL(k_pv,    dim3(BB * HH * (NN / 64)), dim3(256), 0, stream, hpT, sB, cB, tB, pack, out);
  hipLaunchKernelGGL(k_mean,  dim3(BB * NN), dim3(256), 0, stream, sB, tB4, cB, pack, outMean);
}